// Round 1
// baseline (1245.858 us; speedup 1.0000x reference)
//
#include <hip/hip_runtime.h>
#include <hip/hip_bf16.h>

// Problem constants
constexpr int Bn = 4;
constexpr int Sn = 4096;
constexpr int Dn = 256;
constexpr int Cn = 8921;
constexpr int BM = 160;              // c-rows per block; 56*160 = 8960 >= 8921
constexpr int NCB = 56;
constexpr int NIT = Sn / 128;        // 32 s-tiles of 128

typedef unsigned short u16;
typedef short v8s __attribute__((ext_vector_type(8)));   // 8 bf16 (4 VGPRs)
typedef float v4f __attribute__((ext_vector_type(4)));

// workspace layout (bytes) -- only bf16 copies of W, x, xT (~21.4 MB)
constexpr size_t OFF_W  = 0;
constexpr size_t OFF_X  = OFF_W  + (size_t)8960 * Dn * 2;
constexpr size_t OFF_XT = OFF_X  + (size_t)Bn * Sn * Dn * 2;
constexpr size_t WS_NEED = OFF_XT + (size_t)Bn * Sn * Dn * 2;

__device__ __forceinline__ u16 f2bs(float x) { __bf16 b = (__bf16)x; return __builtin_bit_cast(u16, b); }

// async global->LDS, 16B per lane; LDS dest must be wave-uniform base + lane*16
#define GLD16(g_, l_) __builtin_amdgcn_global_load_lds( \
    (const __attribute__((address_space(1))) unsigned int*)(g_), \
    (__attribute__((address_space(3))) unsigned int*)(l_), 16, 0, 0)

// ---------------- Kernel 1a: W -> bf16 ----------------
__global__ __launch_bounds__(256) void k_conv_w(const float* __restrict__ Wsrc,
                                                u16* __restrict__ Wb) {
    int idx = blockIdx.x * 256 + threadIdx.x;
    if (idx < (Cn * Dn) / 4) {
        float4 v = ((const float4*)Wsrc)[idx];
        ushort4 o; o.x = f2bs(v.x); o.y = f2bs(v.y); o.z = f2bs(v.z); o.w = f2bs(v.w);
        ((ushort4*)Wb)[idx] = o;
    }
}

// ---------------- Kernel 1b: x -> bf16 and xT -> bf16 ----------------
// grid (S/64, D/64, B), block 256
__global__ __launch_bounds__(256) void k_conv_x(const float* __restrict__ x,
                                                u16* __restrict__ xb,
                                                u16* __restrict__ xt) {
    __shared__ u16 tile[64][65];
    const int t  = threadIdx.x;
    const int b  = blockIdx.z;
    const int s0 = blockIdx.x * 64, d0 = blockIdx.y * 64;
    const float* xs = x + (size_t)b * Sn * Dn;
    u16* xbb = xb + (size_t)b * Sn * Dn;
    u16* xtb = xt + (size_t)b * Dn * Sn;
    const int rr = t >> 4, cc = (t & 15) * 4;
#pragma unroll
    for (int i = 0; i < 4; i++) {
        int srow = i * 16 + rr;
        float4 v = *(const float4*)(xs + (size_t)(s0 + srow) * Dn + d0 + cc);
        ushort4 o; o.x = f2bs(v.x); o.y = f2bs(v.y); o.z = f2bs(v.z); o.w = f2bs(v.w);
        *(ushort4*)(xbb + (size_t)(s0 + srow) * Dn + d0 + cc) = o;
        tile[srow][cc] = o.x; tile[srow][cc + 1] = o.y; tile[srow][cc + 2] = o.z; tile[srow][cc + 3] = o.w;
    }
    __syncthreads();
#pragma unroll
    for (int i = 0; i < 4; i++) {
        int drow = i * 16 + rr;
        ushort4 o;
        o.x = tile[cc][drow]; o.y = tile[cc + 1][drow]; o.z = tile[cc + 2][drow]; o.w = tile[cc + 3][drow];
        *(ushort4*)(xtb + (size_t)(d0 + drow) * Sn + s0 + cc) = o;
    }
}

// ---------------- fused main kernel ----------------
// LDS byte offsets (total 115328 B = 112.6 KB)
constexpr int L_XB0 = 0;          // [128][64] bf16 QK B-tile dbuf  (16 KB)
constexpr int L_XB1 = 16384;
constexpr int L_WB0 = 32768;      // [160][64] bf16 QK A-tile dbuf  (20 KB)
constexpr int L_WB1 = 53248;
constexpr int L_E   = 73728;      // [160][128] bf16 e-tile, oct ^ (row&15) swizzle (40 KB)
constexpr int L_L   = 114688;     // 160 floats: l / rinv
constexpr int L_TOT = 114688 + 640;
// PV xT halves alias the (idle during PV) QK buffers:
//   XT0 @ bytes 0..32767, XT1 @ bytes 32768..65535

__device__ __forceinline__ void stage_xb(const u16* xbb, char* lds, int t, int it, int ks, int buf) {
#pragma unroll
    for (int i = 0; i < 2; i++) {
        int q = i * 512 + t;
        int row = q >> 3, oct = q & 7, lc = oct ^ (row & 7);
        GLD16(xbb + (size_t)(it * 128 + row) * Dn + ks * 64 + lc * 8,
              lds + (buf ? L_XB1 : L_XB0) + q * 16);
    }
}

__device__ __forceinline__ void stage_wb(const u16* Wb, char* lds, int t, int c0, int ks, int buf) {
#pragma unroll
    for (int i = 0; i < 3; i++) {
        int q = i * 512 + t;
        if (q < 1280) {                    // 160 rows x 8 chunks; i=2 active on waves 0-3 only
            int row = q >> 3, oct = q & 7, lc = oct ^ (row & 7);
            int grow = c0 + row; if (grow >= Cn) grow = Cn - 1;   // clamp padded C rows
            GLD16(Wb + (size_t)grow * Dn + ks * 64 + lc * 8,
                  lds + (buf ? L_WB1 : L_WB0) + q * 16);
        }
    }
}

// one 160x128 QK tile: scores[c0+0:160][it*128:+128], acc[mi][ni] per wave (wm,wn)
__device__ __forceinline__ void qk_it(const u16* Wb, const u16* xbb, char* lds,
                                      int t, int c0, int it, v4f (&acc)[5][2]) {
    const int l  = t & 63, w = t >> 6;
    const int wm = w >> 2, wn = w & 3;
    const int lr = l & 15, lq = l >> 4;
    stage_xb(xbb, lds, t, it, 0, 0);
    stage_wb(Wb, lds, t, c0, 0, 0);
    __syncthreads();
#pragma unroll
    for (int ks = 0; ks < 4; ks++) {
        if (ks < 3) {                       // prefetch next K-slab while computing this one
            stage_xb(xbb, lds, t, it, ks + 1, (ks + 1) & 1);
            stage_wb(Wb, lds, t, c0, ks + 1, (ks + 1) & 1);
        }
        const u16* A  = (const u16*)(lds + ((ks & 1) ? L_WB1 : L_WB0));
        const u16* Bx = (const u16*)(lds + ((ks & 1) ? L_XB1 : L_XB0));
#pragma unroll
        for (int kc = 0; kc < 2; kc++) {
            v8s af[5], bf[2];
#pragma unroll
            for (int mi = 0; mi < 5; mi++) {
                int row = wm * 80 + mi * 16 + lr;
                int oct = (kc * 4 + lq) ^ (row & 7);
                af[mi] = *(const v8s*)(A + row * 64 + oct * 8);
            }
#pragma unroll
            for (int ni = 0; ni < 2; ni++) {
                int row = wn * 32 + ni * 16 + lr;
                int oct = (kc * 4 + lq) ^ (row & 7);
                bf[ni] = *(const v8s*)(Bx + row * 64 + oct * 8);
            }
#pragma unroll
            for (int mi = 0; mi < 5; mi++)
#pragma unroll
                for (int ni = 0; ni < 2; ni++)
                    acc[mi][ni] = __builtin_amdgcn_mfma_f32_16x16x32_bf16(af[mi], bf[ni], acc[mi][ni], 0, 0, 0);
        }
        __syncthreads();
    }
}

// grid (56, B), block 512 (8 waves: wm = w>>2 over c-halves of 80, wn = w&3)
__global__ __launch_bounds__(512, 2) void k_main(const u16* __restrict__ Wb,
                                                 const u16* __restrict__ xb,
                                                 const u16* __restrict__ xt,
                                                 float* __restrict__ out) {
    __shared__ __align__(16) char lds[L_TOT];
    const int t  = threadIdx.x;
    const int c0 = blockIdx.x * BM;
    const int b  = blockIdx.y;
    const u16* xbb = xb + (size_t)b * Sn * Dn;
    const u16* xtb = xt + (size_t)b * Dn * Sn;
    const int l  = t & 63, w = t >> 6;
    const int wm = w >> 2, wn = w & 3;
    const int lr = l & 15, lq = l >> 4;
    float* lbuf = (float*)(lds + L_L);
    if (t < BM) lbuf[t] = 0.f;

    // ---------- phase B: l[c] = sum_s exp(score) (recompute later instead of stashing e) ----------
#pragma unroll 1
    for (int it = 0; it < NIT; ++it) {
        v4f acc[5][2] = {};
        qk_it(Wb, xbb, lds, t, c0, it, acc);
#pragma unroll
        for (int mi = 0; mi < 5; mi++)
#pragma unroll
            for (int r = 0; r < 4; r++) {
                float s = __expf(acc[mi][0][r]) + __expf(acc[mi][1][r]);
                s += __shfl_xor(s, 1); s += __shfl_xor(s, 2);
                s += __shfl_xor(s, 4); s += __shfl_xor(s, 8);
                if (lr == 0) atomicAdd(&lbuf[wm * 80 + mi * 16 + lq * 4 + r], s);
            }
    }
    __syncthreads();
    if (t < BM) lbuf[t] = 1.f / lbuf[t];
    __syncthreads();
    float rv[5][4];
#pragma unroll
    for (int mi = 0; mi < 5; mi++)
#pragma unroll
        for (int r = 0; r < 4; r++)
            rv[mi][r] = lbuf[wm * 80 + mi * 16 + lq * 4 + r];

    // ---------- phase C: recompute QK, write attn, accumulate PV, write logits ----------
    float* attn = out + (size_t)Bn * Cn * Dn + (size_t)b * Cn * Sn;
    u16* sE = (u16*)(lds + L_E);
    v4f accp[5][4] = {};

#pragma unroll 1
    for (int it = 0; it < NIT; ++it) {
        v4f acc[5][2] = {};
        qk_it(Wb, xbb, lds, t, c0, it, acc);    // ends with barrier

        // issue xT half 0 (s-window it*128 .. +64) into XB region (QK reads done)
#pragma unroll
        for (int i = 0; i < 4; i++) {
            int q = i * 512 + t;
            int row = q >> 3, oct = q & 7, lc = oct ^ (row & 7);
            GLD16(xtb + (size_t)row * Sn + it * 128 + lc * 8, lds + q * 16);
        }
        // exp in regs; e -> LDS bf16 (oct ^ (row&15) swizzle, conflict-free frag reads)
#pragma unroll
        for (int mi = 0; mi < 5; mi++)
#pragma unroll
            for (int ni = 0; ni < 2; ni++)
#pragma unroll
                for (int r = 0; r < 4; r++) {
                    float e = __expf(acc[mi][ni][r]);
                    acc[mi][ni][r] = e;
                    int rloc = lq * 4 + r;                 // == row & 15
                    int row = wm * 80 + mi * 16 + rloc;
                    int col = wn * 32 + ni * 16 + lr;
                    int oct = (col >> 3) ^ rloc;
                    sE[row * 128 + oct * 8 + (lr & 7)] = f2bs(e);
                }
        // attn = e_f32 * rinv, straight from registers (64B-contiguous per instr)
#pragma unroll
        for (int mi = 0; mi < 5; mi++)
#pragma unroll
            for (int r = 0; r < 4; r++) {
                int c = c0 + wm * 80 + mi * 16 + lq * 4 + r;
                if (c < Cn) {
                    float rvv = rv[mi][r];
#pragma unroll
                    for (int ni = 0; ni < 2; ni++) {
                        int s = it * 128 + wn * 32 + ni * 16 + lr;
                        attn[(size_t)c * Sn + s] = acc[mi][ni][r] * rvv;
                    }
                }
            }
        __syncthreads();   // e-tile + xT half 0 ready

#pragma unroll
        for (int ks2 = 0; ks2 < 2; ks2++) {
            if (ks2 == 0) {
                // prefetch xT half 1 into (idle) WB region while PV-0 computes
#pragma unroll
                for (int i = 0; i < 4; i++) {
                    int q = i * 512 + t;
                    int row = q >> 3, oct = q & 7, lc = oct ^ (row & 7);
                    GLD16(xtb + (size_t)row * Sn + it * 128 + 64 + lc * 8, lds + 32768 + q * 16);
                }
            }
            const u16* X = (const u16*)(lds + (ks2 ? 32768 : 0));
#pragma unroll
            for (int kc = 0; kc < 2; kc++) {
                v8s ae[5], bt[4];
#pragma unroll
                for (int mi = 0; mi < 5; mi++) {
                    int row = wm * 80 + mi * 16 + lr;           // row & 15 == lr
                    int oct = ((ks2 * 2 + kc) * 4 + lq) ^ lr;
                    ae[mi] = *(const v8s*)(sE + row * 128 + oct * 8);
                }
#pragma unroll
                for (int ni = 0; ni < 4; ni++) {
                    int row = wn * 64 + ni * 16 + lr;
                    int oct = (kc * 4 + lq) ^ (row & 7);
                    bt[ni] = *(const v8s*)(X + row * 64 + oct * 8);
                }
#pragma unroll
                for (int mi = 0; mi < 5; mi++)
#pragma unroll
                    for (int ni = 0; ni < 4; ni++)
                        accp[mi][ni] = __builtin_amdgcn_mfma_f32_16x16x32_bf16(ae[mi], bt[ni], accp[mi][ni], 0, 0, 0);
            }
            __syncthreads();
        }
    }

    // epilogue: logits = accp * rinv
#pragma unroll
    for (int mi = 0; mi < 5; mi++)
#pragma unroll
        for (int r = 0; r < 4; r++) {
            int c = c0 + wm * 80 + mi * 16 + lq * 4 + r;
            if (c < Cn) {
                float rvv = rv[mi][r];
#pragma unroll
                for (int ni = 0; ni < 4; ni++) {
                    int d = wn * 64 + ni * 16 + lr;
                    out[((size_t)b * Cn + c) * Dn + d] = accp[mi][ni][r] * rvv;
                }
            }
        }
}

extern "C" void kernel_launch(void* const* d_in, const int* in_sizes, int n_in,
                              void* d_out, int out_size, void* d_ws, size_t ws_size,
                              hipStream_t stream) {
    const float* x = (const float*)d_in[0];   // [4,4096,256]
    const float* W = (const float*)d_in[1];   // [8921,256]
    float* out = (float*)d_out;               // logits [4,8921,256] then attn [4,8921,4096]
    if (ws_size < WS_NEED) return;            // ~21.4 MB scratch required

    char* ws = (char*)d_ws;
    u16* Wb = (u16*)(ws + OFF_W);
    u16* xb = (u16*)(ws + OFF_X);
    u16* xt = (u16*)(ws + OFF_XT);

    k_conv_w<<<(Cn * Dn / 4 + 255) / 256, 256, 0, stream>>>(W, Wb);
    k_conv_x<<<dim3(Sn / 64, Dn / 64, Bn), 256, 0, stream>>>(x, xb, xt);
    k_main<<<dim3(NCB, Bn), 512, 0, stream>>>(Wb, xb, xt, out);
}

// Round 3
// 1216.130 us; speedup vs baseline: 1.0244x; 1.0244x over previous
//
#include <hip/hip_runtime.h>
#include <hip/hip_bf16.h>

// Problem constants
constexpr int Bn   = 4;
constexpr int Sn   = 4096;
constexpr int Dn   = 256;
constexpr int Cn   = 8921;
constexpr int Cpad = 8960;
constexpr int BM   = 64;            // c-rows per block
constexpr int NCB  = 140;           // ceil(8921/64); 140*4 = 560 blocks
constexpr int NIT  = 32;            // s-tiles of 128

typedef unsigned short u16;
typedef short v8s __attribute__((ext_vector_type(8)));   // 8 bf16 (4 VGPRs)
typedef float v4f __attribute__((ext_vector_type(4)));

// workspace layout (bytes): bf16 W/x/xT + l + e-stash  (~315 MB, same as proven round-0 layout)
constexpr size_t OFF_W  = 0;
constexpr size_t OFF_X  = OFF_W  + (size_t)Cpad * Dn * 2;
constexpr size_t OFF_XT = OFF_X  + (size_t)Bn * Sn * Dn * 2;
constexpr size_t OFF_L  = OFF_XT + (size_t)Bn * Sn * Dn * 2;
constexpr size_t OFF_E  = OFF_L  + (size_t)Bn * Cpad * 4;
constexpr size_t WS_NEED = OFF_E + (size_t)Bn * Cpad * Sn * 2;

__device__ __forceinline__ u16 f2bs(float x) { __bf16 b = (__bf16)x; return __builtin_bit_cast(u16, b); }
__device__ __forceinline__ float b2f(u16 u)  { return __uint_as_float(((unsigned)u) << 16); }

#define GLD16(g_, l_) __builtin_amdgcn_global_load_lds( \
    (const __attribute__((address_space(1))) unsigned int*)(g_), \
    (__attribute__((address_space(3))) unsigned int*)(l_), 16, 0, 0)

// ---------------- Kernel 1a: W -> bf16 ----------------
__global__ __launch_bounds__(256) void k_conv_w(const float* __restrict__ Wsrc,
                                                u16* __restrict__ Wb) {
    int idx = blockIdx.x * 256 + threadIdx.x;
    if (idx < (Cn * Dn) / 4) {
        float4 v = ((const float4*)Wsrc)[idx];
        ushort4 o; o.x = f2bs(v.x); o.y = f2bs(v.y); o.z = f2bs(v.z); o.w = f2bs(v.w);
        ((ushort4*)Wb)[idx] = o;
    }
}

// ---------------- Kernel 1b: x -> bf16 and xT -> bf16 ----------------
__global__ __launch_bounds__(256) void k_conv_x(const float* __restrict__ x,
                                                u16* __restrict__ xb,
                                                u16* __restrict__ xt) {
    __shared__ u16 tile[64][65];
    const int t  = threadIdx.x;
    const int b  = blockIdx.z;
    const int s0 = blockIdx.x * 64, d0 = blockIdx.y * 64;
    const float* xs = x + (size_t)b * Sn * Dn;
    u16* xbb = xb + (size_t)b * Sn * Dn;
    u16* xtb = xt + (size_t)b * Dn * Sn;
    const int rr = t >> 4, cc = (t & 15) * 4;
#pragma unroll
    for (int i = 0; i < 4; i++) {
        int srow = i * 16 + rr;
        float4 v = *(const float4*)(xs + (size_t)(s0 + srow) * Dn + d0 + cc);
        ushort4 o; o.x = f2bs(v.x); o.y = f2bs(v.y); o.z = f2bs(v.z); o.w = f2bs(v.w);
        *(ushort4*)(xbb + (size_t)(s0 + srow) * Dn + d0 + cc) = o;
        tile[srow][cc] = o.x; tile[srow][cc + 1] = o.y; tile[srow][cc + 2] = o.z; tile[srow][cc + 3] = o.w;
    }
    __syncthreads();
#pragma unroll
    for (int i = 0; i < 4; i++) {
        int drow = i * 16 + rr;
        ushort4 o;
        o.x = tile[cc][drow]; o.y = tile[cc + 1][drow]; o.z = tile[cc + 2][drow]; o.w = tile[cc + 3][drow];
        *(ushort4*)(xtb + (size_t)(d0 + drow) * Sn + s0 + cc) = o;
    }
}

// ---------------- fused main kernel ----------------
// LDS byte map (total 65792 B -> 2 blocks/CU):
//   XB0 [128][64] bf16 @ 0      (16 KB)   } QK B-tile dbuf; aliased by xT [256][32] quarters in PV
//   XB1            @ 16384      (16 KB)
//   WB0 [64][64]  @ 32768       ( 8 KB)   } QK A-tile dbuf
//   WB1            @ 40960      ( 8 KB)
//   E   [64][128] @ 49152       (16 KB)   e-tile, oct ^ (row&15) swizzle
//   lbuf 64 f32   @ 65536
constexpr int L_WB = 32768;
constexpr int L_E  = 49152;
constexpr int L_LB = 65536;
constexpr int L_TOT = 65792;

__global__ __launch_bounds__(512, 4) void k_main(const u16* __restrict__ Wb,
                                                 const u16* __restrict__ xb,
                                                 const u16* __restrict__ xt,
                                                 u16* __restrict__ est,
                                                 float* __restrict__ lsum,
                                                 float* __restrict__ out) {
    __shared__ __align__(16) char lds[L_TOT];
    // bijective XCD swizzle: 560 = 8 * 70 -> XCD i gets 70 contiguous (batch, c-chunk) blocks
    const int bid = blockIdx.x;
    const int nid = (bid & 7) * 70 + (bid >> 3);
    const int b = nid / NCB, cblk = nid % NCB;
    const int c0 = cblk * BM;

    const int t = threadIdx.x;
    const int w = t >> 6, l = t & 63;
    const int lr = l & 15, lq = l >> 4;
    const int wm = w >> 2, wn = w & 3;
    const u16* xbb = xb + (size_t)b * Sn * Dn;
    const u16* xtb = xt + (size_t)b * Dn * Sn;
    u16* sE = (u16*)(lds + L_E);
    float* lbuf = (float*)(lds + L_LB);
    u16* estash = est + (size_t)b * Cpad * Sn + (size_t)c0 * Sn;

    // stage helpers ------------------------------------------------------
    auto stage_xb = [&](int it, int ks, int buf) {
#pragma unroll
        for (int i = 0; i < 2; i++) {
            int q = i * 512 + t;
            int row = q >> 3, pc = q & 7, lc = pc ^ (row & 7);
            GLD16(xbb + (size_t)(it * 128 + row) * Dn + ks * 64 + lc * 8, lds + buf * 16384 + q * 16);
        }
    };
    auto stage_wb = [&](int ks, int buf) {
        int row = t >> 3, pc = t & 7, lc = pc ^ (row & 7);
        int grow = c0 + row; if (grow >= Cn) grow = Cn - 1;
        GLD16(Wb + (size_t)grow * Dn + ks * 64 + lc * 8, lds + L_WB + buf * 8192 + t * 16);
    };
    auto stage_xt = [&](int it, int q4, int buf) {   // xT quarter [256 d][32 s] into XB slot
#pragma unroll
        for (int i = 0; i < 2; i++) {
            int q = i * 512 + t;
            int row = q >> 2, c2 = q & 3, lc = c2 ^ (row & 3);
            GLD16(xtb + (size_t)row * Sn + it * 128 + q4 * 32 + lc * 8, lds + buf * 16384 + q * 16);
        }
    };

    v4f accp[2][4] = {};

    // prologue
    if (t < BM) lbuf[t] = 0.f;
    stage_xb(0, 0, 0); stage_wb(0, 0);
    __syncthreads();

#pragma unroll 1
    for (int it = 0; it < NIT; ++it) {
        // ---- QK phase: scores[64 c][128 s], K=256 in 4 slabs of 64 ----
        v4f acc[2][2] = {};
#pragma unroll
        for (int ks = 0; ks < 4; ks++) {
            if (ks < 3) { stage_xb(it, ks + 1, (ks + 1) & 1); stage_wb(ks + 1, (ks + 1) & 1); }
            const u16* A  = (const u16*)(lds + L_WB + (ks & 1) * 8192);
            const u16* Bx = (const u16*)(lds + (ks & 1) * 16384);
#pragma unroll
            for (int kc = 0; kc < 2; kc++) {
                v8s af[2], bf[2];
#pragma unroll
                for (int mi = 0; mi < 2; mi++) {
                    int row = wm * 32 + mi * 16 + lr;
                    int oct = (kc * 4 + lq) ^ (row & 7);
                    af[mi] = *(const v8s*)(A + row * 64 + oct * 8);
                }
#pragma unroll
                for (int ni = 0; ni < 2; ni++) {
                    int row = wn * 32 + ni * 16 + lr;
                    int oct = (kc * 4 + lq) ^ (row & 7);
                    bf[ni] = *(const v8s*)(Bx + row * 64 + oct * 8);
                }
#pragma unroll
                for (int mi = 0; mi < 2; mi++)
#pragma unroll
                    for (int ni = 0; ni < 2; ni++)
                        acc[mi][ni] = __builtin_amdgcn_mfma_f32_16x16x32_bf16(af[mi], bf[ni], acc[mi][ni], 0, 0, 0);
            }
            __syncthreads();
        }

        // ---- e phase: exp, e -> LDS E (swizzled), l partial sums ----
        stage_xt(it, 0, 0); stage_xt(it, 1, 1);      // XB fully dead -> stage PV quarters 0,1
#pragma unroll
        for (int mi = 0; mi < 2; mi++)
#pragma unroll
            for (int r = 0; r < 4; r++) {
                float e0 = __expf(acc[mi][0][r]);
                float e1 = __expf(acc[mi][1][r]);
                int rloc = lq * 4 + r;
                int row = wm * 32 + mi * 16 + rloc;   // row & 15 == rloc
                int col0 = wn * 32 + lr;
                int col1 = wn * 32 + 16 + lr;
                sE[row * 128 + ((col0 >> 3) ^ rloc) * 8 + (lr & 7)] = f2bs(e0);
                sE[row * 128 + ((col1 >> 3) ^ rloc) * 8 + (lr & 7)] = f2bs(e1);
                float s = e0 + e1;
                s += __shfl_xor(s, 1); s += __shfl_xor(s, 2);
                s += __shfl_xor(s, 4); s += __shfl_xor(s, 8);
                if (lr == 0) atomicAdd(&lbuf[row], s);
            }
        __syncthreads();   // E complete, xT q0/q1 landed

        // ---- E -> global stash (coalesced 16B stores, overlaps PV) ----
#pragma unroll
        for (int i = 0; i < 2; i++) {
            int q = i * 512 + t;
            int row = q >> 4, oc = q & 15, oa = oc ^ (row & 15);
            v8s v = *(const v8s*)(sE + row * 128 + oa * 8);
            *(v8s*)(estash + (size_t)row * Sn + it * 128 + oc * 8) = v;
        }

        // ---- PV phase: logits[64 c][256 d] += e[64][128] * xT[256][128]^T ----
#pragma unroll
        for (int q4 = 0; q4 < 4; q4++) {
            const u16* X = (const u16*)(lds + (q4 & 1) * 16384);
            v8s ae[2], bt[4];
#pragma unroll
            for (int mi = 0; mi < 2; mi++) {
                int row = wm * 32 + mi * 16 + lr;     // row & 15 == lr
                int oct = (q4 * 4 + lq) ^ lr;
                ae[mi] = *(const v8s*)(sE + row * 128 + oct * 8);
            }
#pragma unroll
            for (int ni = 0; ni < 4; ni++) {
                int row = wn * 64 + ni * 16 + lr;
                int o4 = lq ^ (row & 3);
                bt[ni] = *(const v8s*)(X + row * 32 + o4 * 8);
            }
#pragma unroll
            for (int mi = 0; mi < 2; mi++)
#pragma unroll
                for (int ni = 0; ni < 4; ni++)
                    accp[mi][ni] = __builtin_amdgcn_mfma_f32_16x16x32_bf16(ae[mi], bt[ni], accp[mi][ni], 0, 0, 0);
            __syncthreads();
            if (q4 < 2)      stage_xt(it, q4 + 2, q4 & 1);          // quarters 2,3
            else if (q4 == 2 && it + 1 < NIT) { stage_xb(it + 1, 0, 0); stage_wb(0, 0); }  // next-it QK slab 0
        }
    }

    // ---- epilogue: logits = accp / l; write l for the scale pass ----
    float rv_[2][4];
#pragma unroll
    for (int mi = 0; mi < 2; mi++)
#pragma unroll
        for (int r = 0; r < 4; r++)
            rv_[mi][r] = 1.f / lbuf[wm * 32 + mi * 16 + lq * 4 + r];
#pragma unroll
    for (int mi = 0; mi < 2; mi++)
#pragma unroll
        for (int r = 0; r < 4; r++) {
            int c = c0 + wm * 32 + mi * 16 + lq * 4 + r;
            if (c < Cn) {
#pragma unroll
                for (int ni = 0; ni < 4; ni++) {
                    int d = wn * 64 + ni * 16 + lr;
                    out[((size_t)b * Cn + c) * Dn + d] = accp[mi][ni][r] * rv_[mi][r];
                }
            }
        }
    if (t < BM) lsum[(size_t)b * Cpad + c0 + t] = lbuf[t];
}

// ---------------- Kernel 3: attn = e / l (streaming) ----------------
// grid (Cn, Bn), block 512: one block per attention row
__global__ __launch_bounds__(512) void k_scale(const u16* __restrict__ est,
                                               const float* __restrict__ lsum,
                                               float* __restrict__ out) {
    const int c = blockIdx.x, b = blockIdx.y;
    const float rv = 1.f / lsum[(size_t)b * Cpad + c];
    const u16* er = est + ((size_t)b * Cpad + c) * Sn;
    float* ar = out + (size_t)Bn * Cn * Dn + ((size_t)b * Cn + c) * Sn;
    const int s = threadIdx.x * 8;
    v8s v = *(const v8s*)(er + s);
    float4 o0, o1;
    o0.x = b2f((u16)v[0]) * rv; o0.y = b2f((u16)v[1]) * rv;
    o0.z = b2f((u16)v[2]) * rv; o0.w = b2f((u16)v[3]) * rv;
    o1.x = b2f((u16)v[4]) * rv; o1.y = b2f((u16)v[5]) * rv;
    o1.z = b2f((u16)v[6]) * rv; o1.w = b2f((u16)v[7]) * rv;
    *(float4*)(ar + s) = o0;
    *(float4*)(ar + s + 4) = o1;
}

extern "C" void kernel_launch(void* const* d_in, const int* in_sizes, int n_in,
                              void* d_out, int out_size, void* d_ws, size_t ws_size,
                              hipStream_t stream) {
    const float* x = (const float*)d_in[0];   // [4,4096,256]
    const float* W = (const float*)d_in[1];   // [8921,256]
    float* out = (float*)d_out;               // logits [4,8921,256] then attn [4,8921,4096]
    if (ws_size < WS_NEED) return;            // ~315 MB scratch required

    char* ws = (char*)d_ws;
    u16*   Wb = (u16*)(ws + OFF_W);
    u16*   xb = (u16*)(ws + OFF_X);
    u16*   xt = (u16*)(ws + OFF_XT);
    float* ls = (float*)(ws + OFF_L);
    u16*   es = (u16*)(ws + OFF_E);

    k_conv_w<<<(Cn * Dn / 4 + 255) / 256, 256, 0, stream>>>(W, Wb);
    k_conv_x<<<dim3(Sn / 64, Dn / 64, Bn), 256, 0, stream>>>(x, xb, xt);
    k_main<<<dim3(NCB * Bn), 512, 0, stream>>>(Wb, xb, xt, es, ls, out);
    k_scale<<<dim3(Cn, Bn), 512, 0, stream>>>(es, ls, out);
}